// Round 1
// baseline (1633.587 us; speedup 1.0000x reference)
//
#include <hip/hip_runtime.h>
#include <stdint.h>

#define NN 100000     // N_SRC == N_TGT
#define NE 1600000
#define DD 128

// ===================== threefry2x32 (JAX-compatible) =====================
__host__ __device__ static inline unsigned rotl32(unsigned x, int r){
  return (x << r) | (x >> (32 - r));
}

__host__ __device__ static inline void tf2x32(unsigned k0, unsigned k1,
                                              unsigned c0, unsigned c1,
                                              unsigned &o0, unsigned &o1)
{
  const unsigned ks2 = k0 ^ k1 ^ 0x1BD11BDAu;
  unsigned x0 = c0 + k0, x1 = c1 + k1;
#define TFR(r) { x0 += x1; x1 = rotl32(x1, (r)); x1 ^= x0; }
  TFR(13) TFR(15) TFR(26) TFR(6)   x0 += k1;  x1 += ks2 + 1u;
  TFR(17) TFR(29) TFR(16) TFR(24)  x0 += ks2; x1 += k0 + 2u;
  TFR(13) TFR(15) TFR(26) TFR(6)   x0 += k0;  x1 += k1 + 3u;
  TFR(17) TFR(29) TFR(16) TFR(24)  x0 += k1;  x1 += ks2 + 4u;
  TFR(13) TFR(15) TFR(26) TFR(6)   x0 += ks2; x1 += k0 + 5u;
#undef TFR
  o0 = x0; o1 = x1;
}

// Dropout scale for flat element j of an [NN,128] tensor under a folded key.
// jax_threefry_partitionable=True semantics: counter = (hi,lo) of uint64 j
// (hi==0 here), 32-bit stream = o0 ^ o1.
__device__ static inline float drop_scale(unsigned k0, unsigned k1, unsigned j)
{
  unsigned o0, o1;
  tf2x32(k0, k1, 0u, j, o0, o1);
  const unsigned bits = o0 ^ o1;
  const float u = __uint_as_float((bits >> 9) | 0x3F800000u) - 1.0f;
  return (u < 0.9f) ? (1.0f / 0.9f) : 0.0f;
}

// ===================== CSR build =====================
__global__ __launch_bounds__(256) void k_count(const int* __restrict__ dst,
                                               int* __restrict__ deg){
  int i = blockIdx.x * 256 + threadIdx.x;
  if (i < NE) atomicAdd(&deg[dst[i]], 1);
}

__global__ __launch_bounds__(512) void k_scan1(const int* __restrict__ deg,
                                               int* __restrict__ part){
  __shared__ int s[512];
  int i = blockIdx.x * 512 + threadIdx.x;
  s[threadIdx.x] = (i < NN) ? deg[i] : 0;
  __syncthreads();
  for (int off = 256; off > 0; off >>= 1){
    if (threadIdx.x < off) s[threadIdx.x] += s[threadIdx.x + off];
    __syncthreads();
  }
  if (threadIdx.x == 0) part[blockIdx.x] = s[0];
}

__global__ __launch_bounds__(512) void k_scan2(int* __restrict__ part, int nb){
  __shared__ int s[512];
  const int t = threadIdx.x;
  const int v = (t < nb) ? part[t] : 0;
  s[t] = v;
  __syncthreads();
  for (int off = 1; off < 512; off <<= 1){
    int u = (t >= off) ? s[t - off] : 0;
    __syncthreads();
    s[t] += u;
    __syncthreads();
  }
  if (t < nb) part[t] = s[t] - v;   // exclusive
}

__global__ __launch_bounds__(512) void k_scan3(const int* __restrict__ deg,
                                               const int* __restrict__ part,
                                               int* __restrict__ ptr,
                                               int* __restrict__ cur){
  __shared__ int s[512];
  int i = blockIdx.x * 512 + threadIdx.x;
  int v = (i < NN) ? deg[i] : 0;
  s[threadIdx.x] = v;
  __syncthreads();
  for (int off = 1; off < 512; off <<= 1){
    int u = (threadIdx.x >= off) ? s[threadIdx.x - off] : 0;
    __syncthreads();
    s[threadIdx.x] += u;
    __syncthreads();
  }
  int excl = s[threadIdx.x] - v + part[blockIdx.x];
  if (i < NN){
    ptr[i] = excl;
    cur[i] = excl;
    if (i == NN - 1) ptr[NN] = excl + v;
  }
}

__global__ __launch_bounds__(256) void k_fill(const int* __restrict__ src,
                                              const int* __restrict__ dst,
                                              int* __restrict__ cur,
                                              int* __restrict__ csr){
  int i = blockIdx.x * 256 + threadIdx.x;
  if (i < NE){
    int pos = atomicAdd(&cur[dst[i]], 1);
    csr[pos] = src[i];
  }
}

// ===================== mean aggregation (pull via CSR) =====================
// block = 256 threads = 2 rows x 128 channels
__global__ __launch_bounds__(256) void k_agg(const float* __restrict__ x,
                                             const int* __restrict__ ptr,
                                             const int* __restrict__ csr,
                                             float* __restrict__ out){
  const int row = blockIdx.x * 2 + (threadIdx.x >> 7);
  const int ch  = threadIdx.x & 127;
  const int beg = ptr[row], end = ptr[row + 1];
  float acc = 0.0f;
  int e = beg;
  for (; e + 3 < end; e += 4){
    int s0 = csr[e], s1 = csr[e + 1], s2 = csr[e + 2], s3 = csr[e + 3];
    acc += x[(size_t)s0 * DD + ch];
    acc += x[(size_t)s1 * DD + ch];
    acc += x[(size_t)s2 * DD + ch];
    acc += x[(size_t)s3 * DD + ch];
  }
  for (; e < end; ++e) acc += x[(size_t)csr[e] * DD + ch];
  const int cnt = end - beg;
  const float inv = (cnt > 0) ? (1.0f / (float)cnt) : 1.0f;  // /max(cnt,1)
  out[(size_t)row * DD + ch] = acc * inv;
}

// ===================== fused layer GEMM =====================
// H = dropout(leaky_relu(Am@Wl + X@Wr + b))    Am,X:[NN,128]  Wl,Wr:[128,128]
// 32 rows/block, K tiled by 32 (8 chunks over the concat K=256).
__global__ __launch_bounds__(256) void k_fused(const float* __restrict__ Am,
    const float* __restrict__ X, const float* __restrict__ Wl,
    const float* __restrict__ Wr, const float* __restrict__ bias,
    float* __restrict__ out, unsigned key0, unsigned key1)
{
  __shared__ __align__(16) float Wt[32][132];
  __shared__ __align__(16) float At[32][36];
  const int t    = threadIdx.x;
  const int g4   = (t >> 5) * 4;     // 4 rows per thread
  const int c4   = (t & 31) * 4;     // 4 cols per thread
  const int row0 = blockIdx.x * 32;
  const int ar   = t >> 3;           // staging: row
  const int ak   = (t & 7) * 4;      // staging: k offset

  float4 acc[4];
  acc[0] = acc[1] = acc[2] = acc[3] = make_float4(0.f, 0.f, 0.f, 0.f);

  for (int chunk = 0; chunk < 8; ++chunk){
    const float* __restrict__ Asrc = (chunk < 4) ? Am : X;
    const float* __restrict__ Wsrc = (chunk < 4) ? Wl : Wr;
    const int kb = (chunk & 3) * 32;

    #pragma unroll
    for (int q = 0; q < 4; ++q){                 // stage 32x128 of W
      int idx = q * 1024 + t * 4;
      int kk = idx >> 7, j = idx & 127;
      *(float4*)&Wt[kk][j] = *(const float4*)&Wsrc[(size_t)(kb + kk) * 128 + j];
    }
    *(float4*)&At[ar][ak] =                      // stage 32x32 of A/X
        *(const float4*)&Asrc[(size_t)(row0 + ar) * 128 + kb + ak];
    __syncthreads();

    #pragma unroll
    for (int kk = 0; kk < 32; kk += 4){
      const float4 w0 = *(const float4*)&Wt[kk + 0][c4];
      const float4 w1 = *(const float4*)&Wt[kk + 1][c4];
      const float4 w2 = *(const float4*)&Wt[kk + 2][c4];
      const float4 w3 = *(const float4*)&Wt[kk + 3][c4];
      #pragma unroll
      for (int i = 0; i < 4; ++i){
        const float4 a = *(const float4*)&At[g4 + i][kk];
        acc[i].x += a.x * w0.x + a.y * w1.x + a.z * w2.x + a.w * w3.x;
        acc[i].y += a.x * w0.y + a.y * w1.y + a.z * w2.y + a.w * w3.y;
        acc[i].z += a.x * w0.z + a.y * w1.z + a.z * w2.z + a.w * w3.z;
        acc[i].w += a.x * w0.w + a.y * w1.w + a.z * w2.w + a.w * w3.w;
      }
    }
    __syncthreads();
  }

  const float4 bj = *(const float4*)&bias[c4];
  #pragma unroll
  for (int i = 0; i < 4; ++i){
    const int r = row0 + g4 + i;
    float v[4] = { acc[i].x + bj.x, acc[i].y + bj.y,
                   acc[i].z + bj.z, acc[i].w + bj.w };
    float ov[4];
    #pragma unroll
    for (int cc = 0; cc < 4; ++cc){
      float h = v[cc];
      h = (h >= 0.f) ? h : 0.01f * h;                       // leaky_relu
      unsigned j = (unsigned)r * 128u + (unsigned)(c4 + cc);
      ov[cc] = h * drop_scale(key0, key1, j);               // dropout
    }
    *(float4*)&out[(size_t)r * 128 + c4] =
        make_float4(ov[0], ov[1], ov[2], ov[3]);
  }
}

// ===================== output GEMM (no activation) =====================
__global__ __launch_bounds__(256) void k_out(const float* __restrict__ H,
    const float* __restrict__ W, const float* __restrict__ bias,
    float* __restrict__ out)
{
  __shared__ __align__(16) float Wt[32][68];
  __shared__ __align__(16) float At[32][36];
  const int t    = threadIdx.x;
  const int g2   = (t >> 4) * 2;
  const int c4   = (t & 15) * 4;
  const int row0 = blockIdx.x * 32;
  const int ar   = t >> 3;
  const int ak   = (t & 7) * 4;

  float4 acc[2];
  acc[0] = acc[1] = make_float4(0.f, 0.f, 0.f, 0.f);

  for (int chunk = 0; chunk < 4; ++chunk){
    const int kb = chunk * 32;
    #pragma unroll
    for (int q = 0; q < 2; ++q){                 // stage 32x64 of W
      int idx = q * 1024 + t * 4;
      int kk = idx >> 6, j = idx & 63;
      *(float4*)&Wt[kk][j] = *(const float4*)&W[(size_t)(kb + kk) * 64 + j];
    }
    *(float4*)&At[ar][ak] =
        *(const float4*)&H[(size_t)(row0 + ar) * 128 + kb + ak];
    __syncthreads();

    #pragma unroll
    for (int kk = 0; kk < 32; kk += 4){
      const float4 w0 = *(const float4*)&Wt[kk + 0][c4];
      const float4 w1 = *(const float4*)&Wt[kk + 1][c4];
      const float4 w2 = *(const float4*)&Wt[kk + 2][c4];
      const float4 w3 = *(const float4*)&Wt[kk + 3][c4];
      #pragma unroll
      for (int i = 0; i < 2; ++i){
        const float4 a = *(const float4*)&At[g2 + i][kk];
        acc[i].x += a.x * w0.x + a.y * w1.x + a.z * w2.x + a.w * w3.x;
        acc[i].y += a.x * w0.y + a.y * w1.y + a.z * w2.y + a.w * w3.y;
        acc[i].z += a.x * w0.z + a.y * w1.z + a.z * w2.z + a.w * w3.z;
        acc[i].w += a.x * w0.w + a.y * w1.w + a.z * w2.w + a.w * w3.w;
      }
    }
    __syncthreads();
  }
  const float4 bj = *(const float4*)&bias[c4];
  #pragma unroll
  for (int i = 0; i < 2; ++i){
    const int r = row0 + g2 + i;
    *(float4*)&out[(size_t)r * 64 + c4] =
        make_float4(acc[i].x + bj.x, acc[i].y + bj.y,
                    acc[i].z + bj.z, acc[i].w + bj.w);
  }
}

// ===================== launch =====================
extern "C" void kernel_launch(void* const* d_in, const int* in_sizes, int n_in,
                              void* d_out, int out_size, void* d_ws, size_t ws_size,
                              hipStream_t stream)
{
  const float* x_src  = (const float*)d_in[0];
  const float* x_tgt  = (const float*)d_in[1];
  const float* Wl_tgt = (const float*)d_in[2];
  const float* bl_tgt = (const float*)d_in[3];
  const float* Wr_tgt = (const float*)d_in[4];
  const float* Wl_src = (const float*)d_in[5];
  const float* bl_src = (const float*)d_in[6];
  const float* Wr_src = (const float*)d_in[7];
  const float* W_o    = (const float*)d_in[8];
  const float* b_o    = (const float*)d_in[9];
  const int*   e_src  = (const int*)d_in[10];
  const int*   e_dst  = (const int*)d_in[11];
  const int*   r_src  = (const int*)d_in[12];
  const int*   r_dst  = (const int*)d_in[13];
  float* out = (float*)d_out;
  (void)in_sizes; (void)n_in; (void)out_size; (void)ws_size;

  char* ws = (char*)d_ws;
  size_t off = 0;
  auto alloc = [&](size_t bytes) -> char* {
    char* p = ws + off; off += (bytes + 255) & ~(size_t)255; return p;
  };
  float* A     = (float*)alloc((size_t)NN * DD * 4);   // agg scratch
  float* B     = (float*)alloc((size_t)NN * DD * 4);   // h_t(l0), then h_s(l1)
  float* C     = (float*)alloc((size_t)NN * DD * 4);   // h_s(l0)
  int*   deg_t = (int*)alloc((size_t)NN * 4);
  int*   deg_s = (int*)alloc((size_t)NN * 4);
  int*   ptr_e = (int*)alloc((size_t)(NN + 1) * 4);
  int*   ptr_r = (int*)alloc((size_t)(NN + 1) * 4);
  int*   cur_e = (int*)alloc((size_t)NN * 4);
  int*   cur_r = (int*)alloc((size_t)NN * 4);
  int*   csr_e = (int*)alloc((size_t)NE * 4);
  int*   csr_r = (int*)alloc((size_t)NE * 4);
  int*   part_e = (int*)alloc(512 * 4);
  int*   part_r = (int*)alloc(512 * 4);

  // dropout keys: fold_in(key(42), d) = threefry([0,42],[0,d]); d in {0,1,3}
  unsigned kt0a, kt0b, ks0a, ks0b, ks1a, ks1b;
  tf2x32(0u, 42u, 0u, 0u, kt0a, kt0b);   // layer0 new_t
  tf2x32(0u, 42u, 0u, 1u, ks0a, ks0b);   // layer0 new_s
  tf2x32(0u, 42u, 0u, 3u, ks1a, ks1b);   // layer1 new_s

  hipMemsetAsync(deg_t, 0, (size_t)NN * 4, stream);
  hipMemsetAsync(deg_s, 0, (size_t)NN * 4, stream);

  const int EB = NE / 256;          // 6250
  const int SB = (NN + 511) / 512;  // 196
  k_count<<<EB, 256, 0, stream>>>(e_dst, deg_t);
  k_count<<<EB, 256, 0, stream>>>(r_dst, deg_s);
  k_scan1<<<SB, 512, 0, stream>>>(deg_t, part_e);
  k_scan1<<<SB, 512, 0, stream>>>(deg_s, part_r);
  k_scan2<<<1, 512, 0, stream>>>(part_e, SB);
  k_scan2<<<1, 512, 0, stream>>>(part_r, SB);
  k_scan3<<<SB, 512, 0, stream>>>(deg_t, part_e, ptr_e, cur_e);
  k_scan3<<<SB, 512, 0, stream>>>(deg_s, part_r, ptr_r, cur_r);
  k_fill<<<EB, 256, 0, stream>>>(e_src, e_dst, cur_e, csr_e);
  k_fill<<<EB, 256, 0, stream>>>(r_src, r_dst, cur_r, csr_r);

  const int GB = NN / 32;           // 3125
  // layer 0, target side: new_t = f(mean(x_src), x_tgt)
  k_agg<<<NN / 2, 256, 0, stream>>>(x_src, ptr_e, csr_e, A);
  k_fused<<<GB, 256, 0, stream>>>(A, x_tgt, Wl_tgt, Wr_tgt, bl_tgt, B, kt0a, kt0b);
  // layer 0, source side: new_s = f(mean(x_tgt), x_src)
  k_agg<<<NN / 2, 256, 0, stream>>>(x_tgt, ptr_r, csr_r, A);
  k_fused<<<GB, 256, 0, stream>>>(A, x_src, Wl_src, Wr_src, bl_src, C, ks0a, ks0b);
  // layer 1, source side only (layer-1 target output is dead)
  k_agg<<<NN / 2, 256, 0, stream>>>(B, ptr_r, csr_r, A);
  k_fused<<<GB, 256, 0, stream>>>(A, C, Wl_src + 128 * 128, Wr_src + 128 * 128,
                                  bl_src + 128, B, ks1a, ks1b);
  // out = h_s1 @ W_out + b_out
  k_out<<<GB, 256, 0, stream>>>(B, W_o, b_o, out);
}

// Round 2
// 912.000 us; speedup vs baseline: 1.7912x; 1.7912x over previous
//
#include <hip/hip_runtime.h>
#include <stdint.h>

#define NN 100000     // N_SRC == N_TGT
#define NE 1600000
#define DD 128

typedef unsigned short u16;
typedef short short8 __attribute__((ext_vector_type(8)));
typedef float floatx4 __attribute__((ext_vector_type(4)));

// ===================== helpers =====================
__device__ static inline u16 f2bf(float f){
  unsigned u = __float_as_uint(f);
  unsigned r = u + 0x7FFFu + ((u >> 16) & 1u);   // RNE
  return (u16)(r >> 16);
}

// ===================== threefry2x32 (JAX-compatible) =====================
__host__ __device__ static inline unsigned rotl32(unsigned x, int r){
  return (x << r) | (x >> (32 - r));
}

__host__ __device__ static inline void tf2x32(unsigned k0, unsigned k1,
                                              unsigned c0, unsigned c1,
                                              unsigned &o0, unsigned &o1)
{
  const unsigned ks2 = k0 ^ k1 ^ 0x1BD11BDAu;
  unsigned x0 = c0 + k0, x1 = c1 + k1;
#define TFR(r) { x0 += x1; x1 = rotl32(x1, (r)); x1 ^= x0; }
  TFR(13) TFR(15) TFR(26) TFR(6)   x0 += k1;  x1 += ks2 + 1u;
  TFR(17) TFR(29) TFR(16) TFR(24)  x0 += ks2; x1 += k0 + 2u;
  TFR(13) TFR(15) TFR(26) TFR(6)   x0 += k0;  x1 += k1 + 3u;
  TFR(17) TFR(29) TFR(16) TFR(24)  x0 += k1;  x1 += ks2 + 4u;
  TFR(13) TFR(15) TFR(26) TFR(6)   x0 += ks2; x1 += k0 + 5u;
#undef TFR
  o0 = x0; o1 = x1;
}

__device__ static inline float drop_scale(unsigned k0, unsigned k1, unsigned j)
{
  unsigned o0, o1;
  tf2x32(k0, k1, 0u, j, o0, o1);
  const unsigned bits = o0 ^ o1;
  const float u = __uint_as_float((bits >> 9) | 0x3F800000u) - 1.0f;
  return (u < 0.9f) ? (1.0f / 0.9f) : 0.0f;
}

// ===================== CSR build =====================
__global__ __launch_bounds__(256) void k_count(const int* __restrict__ dst,
                                               int* __restrict__ deg){
  int i = blockIdx.x * 256 + threadIdx.x;
  if (i < NE) atomicAdd(&deg[dst[i]], 1);
}

__global__ __launch_bounds__(512) void k_scan1(const int* __restrict__ deg,
                                               int* __restrict__ part){
  __shared__ int s[512];
  int i = blockIdx.x * 512 + threadIdx.x;
  s[threadIdx.x] = (i < NN) ? deg[i] : 0;
  __syncthreads();
  for (int off = 256; off > 0; off >>= 1){
    if (threadIdx.x < off) s[threadIdx.x] += s[threadIdx.x + off];
    __syncthreads();
  }
  if (threadIdx.x == 0) part[blockIdx.x] = s[0];
}

__global__ __launch_bounds__(512) void k_scan2(int* __restrict__ part, int nb){
  __shared__ int s[512];
  const int t = threadIdx.x;
  const int v = (t < nb) ? part[t] : 0;
  s[t] = v;
  __syncthreads();
  for (int off = 1; off < 512; off <<= 1){
    int u = (t >= off) ? s[t - off] : 0;
    __syncthreads();
    s[t] += u;
    __syncthreads();
  }
  if (t < nb) part[t] = s[t] - v;   // exclusive
}

__global__ __launch_bounds__(512) void k_scan3(const int* __restrict__ deg,
                                               const int* __restrict__ part,
                                               int* __restrict__ ptr,
                                               int* __restrict__ cur){
  __shared__ int s[512];
  int i = blockIdx.x * 512 + threadIdx.x;
  int v = (i < NN) ? deg[i] : 0;
  s[threadIdx.x] = v;
  __syncthreads();
  for (int off = 1; off < 512; off <<= 1){
    int u = (threadIdx.x >= off) ? s[threadIdx.x - off] : 0;
    __syncthreads();
    s[threadIdx.x] += u;
    __syncthreads();
  }
  int excl = s[threadIdx.x] - v + part[blockIdx.x];
  if (i < NN){
    ptr[i] = excl;
    cur[i] = excl;
    if (i == NN - 1) ptr[NN] = excl + v;
  }
}

__global__ __launch_bounds__(256) void k_fill(const int* __restrict__ src,
                                              const int* __restrict__ dst,
                                              int* __restrict__ cur,
                                              int* __restrict__ csr){
  int i = blockIdx.x * 256 + threadIdx.x;
  if (i < NE){
    int pos = atomicAdd(&cur[dst[i]], 1);
    csr[pos] = src[i];
  }
}

// ===================== fp32 -> bf16 convert (8 elems/thread) =====================
__global__ __launch_bounds__(256) void k_cvt(const float* __restrict__ in,
                                             u16* __restrict__ out, int n8){
  int i = blockIdx.x * 256 + threadIdx.x;
  if (i >= n8) return;
  const float4* p = (const float4*)in + (size_t)i * 2;
  float4 a = p[0], b = p[1];
  u16 v[8] = { f2bf(a.x), f2bf(a.y), f2bf(a.z), f2bf(a.w),
               f2bf(b.x), f2bf(b.y), f2bf(b.z), f2bf(b.w) };
  *(uint4*)(out + (size_t)i * 8) = *(const uint4*)v;
}

// ===================== weight pre-swizzle into B-fragment order ==============
// Wsw[((kt*NT + nt)*64 + lane)*8 + j] = W[kt*32 + (lane>>4)*8 + j][nt*16 + (lane&15)]
// W = concat(Wl[128xN], Wr[128xN]) rows; N=128, NT=8, kt in [0,8)
__global__ __launch_bounds__(256) void k_prepW(const float* __restrict__ Wl,
                                               const float* __restrict__ Wr,
                                               u16* __restrict__ Wsw){
  int idx = blockIdx.x * 256 + threadIdx.x;        // 0..4095
  int lane = idx & 63, tile = idx >> 6;            // tile = kt*8+nt
  int kt = tile >> 3, nt = tile & 7;
  int n = nt * 16 + (lane & 15);
  int kb = kt * 32 + (lane >> 4) * 8;
  u16 v[8];
  #pragma unroll
  for (int j = 0; j < 8; ++j){
    int k = kb + j;
    float w = (k < 128) ? Wl[(size_t)k * 128 + n] : Wr[(size_t)(k - 128) * 128 + n];
    v[j] = f2bf(w);
  }
  *(uint4*)(Wsw + (size_t)idx * 8) = *(const uint4*)v;
}

// W_out: K=128 (kt in [0,4)), N=64 (nt in [0,4))
__global__ __launch_bounds__(256) void k_prepWo(const float* __restrict__ Wo,
                                                u16* __restrict__ Wsw){
  int idx = blockIdx.x * 256 + threadIdx.x;        // 0..1023
  int lane = idx & 63, tile = idx >> 6;            // tile = kt*4+nt
  int kt = tile >> 2, nt = tile & 3;
  int n = nt * 16 + (lane & 15);
  int kb = kt * 32 + (lane >> 4) * 8;
  u16 v[8];
  #pragma unroll
  for (int j = 0; j < 8; ++j)
    v[j] = f2bf(Wo[(size_t)(kb + j) * 64 + n]);
  *(uint4*)(Wsw + (size_t)idx * 8) = *(const uint4*)v;
}

// ===================== mean aggregation (bf16 gather, 1 wave/row) ============
__global__ __launch_bounds__(256) void k_agg(const u16* __restrict__ x,
                                             const int* __restrict__ ptr,
                                             const int* __restrict__ csr,
                                             u16* __restrict__ out){
  const int row  = blockIdx.x * 4 + (threadIdx.x >> 6);
  const int lane = threadIdx.x & 63;
  const int beg = ptr[row], end = ptr[row + 1];
  float a0 = 0.f, a1 = 0.f;
  int e = beg;
  for (; e + 3 < end; e += 4){
    int s0 = csr[e], s1 = csr[e + 1], s2 = csr[e + 2], s3 = csr[e + 3];
    unsigned v0 = *(const unsigned*)(x + (size_t)s0 * DD + lane * 2);
    unsigned v1 = *(const unsigned*)(x + (size_t)s1 * DD + lane * 2);
    unsigned v2 = *(const unsigned*)(x + (size_t)s2 * DD + lane * 2);
    unsigned v3 = *(const unsigned*)(x + (size_t)s3 * DD + lane * 2);
    a0 += __uint_as_float(v0 << 16) + __uint_as_float(v1 << 16)
        + __uint_as_float(v2 << 16) + __uint_as_float(v3 << 16);
    a1 += __uint_as_float(v0 & 0xFFFF0000u) + __uint_as_float(v1 & 0xFFFF0000u)
        + __uint_as_float(v2 & 0xFFFF0000u) + __uint_as_float(v3 & 0xFFFF0000u);
  }
  for (; e < end; ++e){
    unsigned v = *(const unsigned*)(x + (size_t)csr[e] * DD + lane * 2);
    a0 += __uint_as_float(v << 16);
    a1 += __uint_as_float(v & 0xFFFF0000u);
  }
  const int cnt = end - beg;
  const float inv = (cnt > 0) ? (1.0f / (float)cnt) : 1.0f;
  unsigned pack = (unsigned)f2bf(a0 * inv) | ((unsigned)f2bf(a1 * inv) << 16);
  *(unsigned*)(out + (size_t)row * DD + lane * 2) = pack;
}

// ===================== fused layer GEMM via MFMA =============================
// H = dropout(leaky_relu(concat(Am,X) @ Wsw + b)); 4 waves/block, 16 rows/wave
__global__ __launch_bounds__(256) void k_fused(const u16* __restrict__ Am,
    const u16* __restrict__ X, const u16* __restrict__ Wsw,
    const float* __restrict__ bias, u16* __restrict__ outH,
    unsigned key0, unsigned key1)
{
  const int wave = threadIdx.x >> 6, lane = threadIdx.x & 63;
  const int quad = lane >> 4, col0 = lane & 15;
  const int row0 = blockIdx.x * 64 + wave * 16;
  int m = row0 + col0;                 // A-operand row for this lane
  if (m >= NN) m = NN - 1;             // clamp (tail block), stores guarded

  floatx4 acc[8];
  #pragma unroll
  for (int i = 0; i < 8; ++i) acc[i] = (floatx4)0.f;

  #pragma unroll
  for (int kt = 0; kt < 8; ++kt){
    const int k = kt * 32 + quad * 8;
    const u16* ap = (k < 128) ? (Am + (size_t)m * 128 + k)
                              : (X  + (size_t)m * 128 + (k - 128));
    short8 a = *(const short8*)ap;
    #pragma unroll
    for (int nt = 0; nt < 8; ++nt){
      short8 b = *(const short8*)(Wsw + (size_t)(((kt * 8 + nt) * 64 + lane) * 8));
      acc[nt] = __builtin_amdgcn_mfma_f32_16x16x32_bf16(a, b, acc[nt], 0, 0, 0);
    }
  }

  #pragma unroll
  for (int nt = 0; nt < 8; ++nt){
    const int col = nt * 16 + col0;
    const float bj = bias[col];
    #pragma unroll
    for (int rg = 0; rg < 4; ++rg){
      const int r = row0 + quad * 4 + rg;
      if (r < NN){
        float h = acc[nt][rg] + bj;
        h = (h >= 0.f) ? h : 0.01f * h;                     // leaky_relu
        unsigned j = (unsigned)r * 128u + (unsigned)col;
        h *= drop_scale(key0, key1, j);                     // dropout
        outH[(size_t)r * 128 + col] = f2bf(h);
      }
    }
  }
}

// ===================== output GEMM via MFMA (fp32 out) =======================
__global__ __launch_bounds__(256) void k_out(const u16* __restrict__ H,
    const u16* __restrict__ Wsw, const float* __restrict__ bias,
    float* __restrict__ out)
{
  const int wave = threadIdx.x >> 6, lane = threadIdx.x & 63;
  const int quad = lane >> 4, col0 = lane & 15;
  const int row0 = blockIdx.x * 64 + wave * 16;
  int m = row0 + col0;
  if (m >= NN) m = NN - 1;

  floatx4 acc[4];
  #pragma unroll
  for (int i = 0; i < 4; ++i) acc[i] = (floatx4)0.f;

  #pragma unroll
  for (int kt = 0; kt < 4; ++kt){
    short8 a = *(const short8*)(H + (size_t)m * 128 + kt * 32 + quad * 8);
    #pragma unroll
    for (int nt = 0; nt < 4; ++nt){
      short8 b = *(const short8*)(Wsw + (size_t)(((kt * 4 + nt) * 64 + lane) * 8));
      acc[nt] = __builtin_amdgcn_mfma_f32_16x16x32_bf16(a, b, acc[nt], 0, 0, 0);
    }
  }

  #pragma unroll
  for (int nt = 0; nt < 4; ++nt){
    const int col = nt * 16 + col0;
    const float bj = bias[col];
    #pragma unroll
    for (int rg = 0; rg < 4; ++rg){
      const int r = row0 + quad * 4 + rg;
      if (r < NN)
        out[(size_t)r * 64 + col] = acc[nt][rg] + bj;
    }
  }
}

// ===================== launch =====================
extern "C" void kernel_launch(void* const* d_in, const int* in_sizes, int n_in,
                              void* d_out, int out_size, void* d_ws, size_t ws_size,
                              hipStream_t stream)
{
  const float* x_src  = (const float*)d_in[0];
  const float* x_tgt  = (const float*)d_in[1];
  const float* Wl_tgt = (const float*)d_in[2];
  const float* bl_tgt = (const float*)d_in[3];
  const float* Wr_tgt = (const float*)d_in[4];
  const float* Wl_src = (const float*)d_in[5];
  const float* bl_src = (const float*)d_in[6];
  const float* Wr_src = (const float*)d_in[7];
  const float* W_o    = (const float*)d_in[8];
  const float* b_o    = (const float*)d_in[9];
  const int*   e_src  = (const int*)d_in[10];
  const int*   e_dst  = (const int*)d_in[11];
  const int*   r_src  = (const int*)d_in[12];
  const int*   r_dst  = (const int*)d_in[13];
  float* out = (float*)d_out;
  (void)in_sizes; (void)n_in; (void)out_size; (void)ws_size;

  char* ws = (char*)d_ws;
  size_t off = 0;
  auto alloc = [&](size_t bytes) -> char* {
    char* p = ws + off; off += (bytes + 255) & ~(size_t)255; return p;
  };
  u16* Xs    = (u16*)alloc((size_t)NN * DD * 2);   // bf16 x_source
  u16* Xt    = (u16*)alloc((size_t)NN * DD * 2);   // bf16 x_target
  u16* A     = (u16*)alloc((size_t)NN * DD * 2);   // agg scratch (bf16)
  u16* B     = (u16*)alloc((size_t)NN * DD * 2);   // h_t(l0), then h_s(l1)
  u16* C     = (u16*)alloc((size_t)NN * DD * 2);   // h_s(l0)
  u16* Wsw0  = (u16*)alloc(256 * 128 * 2);         // layer0 tgt
  u16* Wsw1  = (u16*)alloc(256 * 128 * 2);         // layer0 src
  u16* Wsw2  = (u16*)alloc(256 * 128 * 2);         // layer1 src
  u16* Wswo  = (u16*)alloc(128 * 64 * 2);          // output
  int* deg_t = (int*)alloc((size_t)NN * 4);
  int* deg_s = (int*)alloc((size_t)NN * 4);
  int* ptr_e = (int*)alloc((size_t)(NN + 1) * 4);
  int* ptr_r = (int*)alloc((size_t)(NN + 1) * 4);
  int* cur_e = (int*)alloc((size_t)NN * 4);
  int* cur_r = (int*)alloc((size_t)NN * 4);
  int* csr_e = (int*)alloc((size_t)NE * 4);
  int* csr_r = (int*)alloc((size_t)NE * 4);
  int* part_e = (int*)alloc(512 * 4);
  int* part_r = (int*)alloc(512 * 4);

  // dropout keys: fold_in(key(42), d) = threefry([0,42],[0,d]); d in {0,1,3}
  unsigned kt0a, kt0b, ks0a, ks0b, ks1a, ks1b;
  tf2x32(0u, 42u, 0u, 0u, kt0a, kt0b);   // layer0 new_t
  tf2x32(0u, 42u, 0u, 1u, ks0a, ks0b);   // layer0 new_s
  tf2x32(0u, 42u, 0u, 3u, ks1a, ks1b);   // layer1 new_s

  hipMemsetAsync(deg_t, 0, (size_t)NN * 4, stream);
  hipMemsetAsync(deg_s, 0, (size_t)NN * 4, stream);

  const int EB = NE / 256;          // 6250
  const int SB = (NN + 511) / 512;  // 196
  const int CB = (NN * DD / 8 + 255) / 256;  // convert blocks

  // independent prep work
  k_cvt<<<CB, 256, 0, stream>>>(x_src, Xs, NN * DD / 8);
  k_cvt<<<CB, 256, 0, stream>>>(x_tgt, Xt, NN * DD / 8);
  k_prepW<<<16, 256, 0, stream>>>(Wl_tgt, Wr_tgt, Wsw0);
  k_prepW<<<16, 256, 0, stream>>>(Wl_src, Wr_src, Wsw1);
  k_prepW<<<16, 256, 0, stream>>>(Wl_src + 128 * 128, Wr_src + 128 * 128, Wsw2);
  k_prepWo<<<4, 256, 0, stream>>>(W_o, Wswo);

  // CSR build
  k_count<<<EB, 256, 0, stream>>>(e_dst, deg_t);
  k_count<<<EB, 256, 0, stream>>>(r_dst, deg_s);
  k_scan1<<<SB, 512, 0, stream>>>(deg_t, part_e);
  k_scan1<<<SB, 512, 0, stream>>>(deg_s, part_r);
  k_scan2<<<1, 512, 0, stream>>>(part_e, SB);
  k_scan2<<<1, 512, 0, stream>>>(part_r, SB);
  k_scan3<<<SB, 512, 0, stream>>>(deg_t, part_e, ptr_e, cur_e);
  k_scan3<<<SB, 512, 0, stream>>>(deg_s, part_r, ptr_r, cur_r);
  k_fill<<<EB, 256, 0, stream>>>(e_src, e_dst, cur_e, csr_e);
  k_fill<<<EB, 256, 0, stream>>>(r_src, r_dst, cur_r, csr_r);

  const int GB = (NN + 63) / 64;    // 1563
  const int AB = NN / 4;            // 25000
  // layer 0, target side: new_t = f(mean(x_src), x_tgt)
  k_agg<<<AB, 256, 0, stream>>>(Xs, ptr_e, csr_e, A);
  k_fused<<<GB, 256, 0, stream>>>(A, Xt, Wsw0, bl_tgt, B, kt0a, kt0b);
  // layer 0, source side: new_s = f(mean(x_tgt), x_src)
  k_agg<<<AB, 256, 0, stream>>>(Xt, ptr_r, csr_r, A);
  k_fused<<<GB, 256, 0, stream>>>(A, Xs, Wsw1, bl_src, C, ks0a, ks0b);
  // layer 1, source side only (layer-1 target output is dead)
  k_agg<<<AB, 256, 0, stream>>>(B, ptr_r, csr_r, A);
  k_fused<<<GB, 256, 0, stream>>>(A, C, Wsw2, bl_src + 128, B, ks1a, ks1b);
  // out = h_s1 @ W_out + b_out
  k_out<<<GB, 256, 0, stream>>>(B, Wswo, b_o, out);
}